// Round 1
// baseline (893.119 us; speedup 1.0000x reference)
//
#include <hip/hip_runtime.h>
#include <stdint.h>

// ---------------------------------------------------------------------------
// ParallaxICBlurModel: depthwise 31x31 conv (3ch x 16 layers) + per-pixel
// alpha-weighted layer sum.  Implicit-GEMM on mfma_f32_16x16x32_bf16.
//   M = 16 pixels per MFMA (2 rows x 8 cols at x-stride 8, sub-offset d)
//   N = 16 layers, K = 31 kernel-rows x 32 (31 taps + 1 zero pad)
// ---------------------------------------------------------------------------

typedef short short8 __attribute__((ext_vector_type(8)));
typedef float f32x4 __attribute__((ext_vector_type(4)));

#define W_IMG   1054          // padded input width/height (H + KS - 1)
#define NKY     31
#define IMG_ROWS 38           // 8 output rows + 30 halo
#define COPY_ELEMS 96         // per-copy span: 64 strip + up to 91 max offset -> 96
#define IMG_ROWB (4 * COPY_ELEMS * 2)   // 768 B: 4 shifted bf16 copies per row
#define BOFF    (IMG_ROWS * IMG_ROWB)   // 29184
#define LDS_BYTES (BOFF + NKY * 64 * 16) // + B-frag table 31744 -> 60928

__device__ __forceinline__ uint16_t f2bf(float f) {
    uint32_t u = __float_as_uint(f);
    uint32_t r = (u + 0x7fffu + ((u >> 16) & 1u)) >> 16;
    return (uint16_t)r;
}

__global__ __launch_bounds__(256) void conv_fused(
    const float* __restrict__ img, const int* __restrict__ idxp,
    const float* __restrict__ wts, const float* __restrict__ alpha,
    float* __restrict__ out)
{
    __shared__ __align__(16) unsigned char sm[LDS_BYTES];

    const int tid = threadIdx.x;
    const int bid = blockIdx.x;
    const int bx = bid & 15;            // 16 x-strips of 64
    const int by = (bid >> 4) & 127;    // 128 y-blocks of 8
    const int ch = bid >> 11;           // 3 channels
    const int x0 = bx << 6;
    const int y0 = by << 3;

    const float* __restrict__ imgc = img + (size_t)ch * (W_IMG * W_IMG);

    // ---- stage image tile: 38 rows x 4 shifted copies x 96 bf16 ----
    // copy c, position P holds img_row[x0 + c + P]
    for (int it = tid; it < IMG_ROWS * 4 * (COPY_ELEMS / 4); it += 256) {
        int g4 = it % 24;
        int rc = it / 24;
        int c = rc & 3;
        int row = rc >> 2;
        int colbase = x0 + c + (g4 << 2);
        const float* gp = imgc + (size_t)(y0 + row) * W_IMG + colbase;
        uint64_t pack = 0;
        #pragma unroll
        for (int e = 0; e < 4; ++e) {
            int col = colbase + e;
            float f = (col < W_IMG) ? gp[e] : 0.0f;
            pack |= (uint64_t)f2bf(f) << (16 * e);
        }
        *(uint64_t*)(sm + row * IMG_ROWB + c * (COPY_ELEMS * 2) + (g4 << 3)) = pack;
    }

    // ---- stage B-fragment table: chunk ky, lane l -> 8 bf16 (16 B) ----
    // B[k][layer]: lane = 16*(k/8) + layer, elem j = k%8, tap kx = 8*(l>>4)+j
    const float* __restrict__ wch = wts + (size_t)ch * 16 * 961;
    for (int it = tid; it < NKY * 64; it += 256) {
        int l = it & 63;
        int ky = it >> 6;
        int layer = l & 15;
        int h = l >> 4;
        union { uint16_t u[8]; short8 s; } pk;
        #pragma unroll
        for (int j = 0; j < 8; ++j) {
            int kx = (h << 3) + j;
            float f = (kx < 31) ? wch[layer * 961 + ky * 31 + kx] : 0.0f;
            pk.u[j] = f2bf(f);
        }
        *(short8*)(sm + BOFF + (it << 4)) = pk.s;
    }

    __syncthreads();

    // ---- main loop ----
    const int lane = tid & 63;
    const int wv = tid >> 6;            // wave -> 2 output rows
    const int lj = lane & 15;           // layer (N) index
    const int hi = lane >> 4;           // k-group
    const int ix = lane & 7;            // A-row: pixel x sub-index (stride 8)
    const int yp = (lane >> 3) & 1;     // A-row bit3: second output row
    const uint32_t lanebase =
        (uint32_t)(2 * wv + yp) * IMG_ROWB + ((uint32_t)(ix + hi) << 4);

    f32x4 acc[8];
    #pragma unroll
    for (int d = 0; d < 8; ++d) { f32x4 z = {0.f, 0.f, 0.f, 0.f}; acc[d] = z; }

    for (int ky = 0; ky < NKY; ++ky) {
        short8 bfrag = *(const short8*)(sm + BOFF + (((ky << 6) + lane) << 4));
        uint32_t kb = lanebase + (uint32_t)ky * IMG_ROWB;
        #pragma unroll
        for (int c = 0; c < 4; ++c) {
            uint32_t a0 = kb + c * (COPY_ELEMS * 2);
            uint64_t q0 = *(const uint64_t*)(sm + a0);       // elems 8s..8s+3 (+0)
            uint64_t q1 = *(const uint64_t*)(sm + a0 + 8);   // elems 8s+4..8s+7
            uint64_t q2 = *(const uint64_t*)(sm + a0 + 16);  // elems 8s+8..8s+11
            union { uint64_t q[2]; short8 s; } fa, fb;
            fa.q[0] = q0; fa.q[1] = q1;                      // d = c
            fb.q[0] = q1; fb.q[1] = q2;                      // d = c + 4
            acc[c]     = __builtin_amdgcn_mfma_f32_16x16x32_bf16(fa.s, bfrag, acc[c],     0, 0, 0);
            acc[c + 4] = __builtin_amdgcn_mfma_f32_16x16x32_bf16(fb.s, bfrag, acc[c + 4], 0, 0, 0);
        }
    }

    // ---- epilogue: multiply by alpha, reduce 16 layer-lanes, store ----
    const int idx = *idxp;
    const float* __restrict__ alro =
        alpha + ((size_t)idx * 16 + lj) * (1024 * 1024);
    float* __restrict__ outc = out + (size_t)ch * (1024 * 1024);

    #pragma unroll
    for (int d = 0; d < 8; ++d) {
        #pragma unroll
        for (int r = 0; r < 4; ++r) {
            int i = 4 * hi + r;                 // D row -> pixel index
            int yy = y0 + 2 * wv + (i >> 3);
            int xx = x0 + d + ((i & 7) << 3);
            float v = acc[d][r] * alro[(size_t)yy * 1024 + xx];
            v += __shfl_xor(v, 1, 64);
            v += __shfl_xor(v, 2, 64);
            v += __shfl_xor(v, 4, 64);
            v += __shfl_xor(v, 8, 64);
            if (lj == 0) outc[(size_t)yy * 1024 + xx] = v;
        }
    }
}

extern "C" void kernel_launch(void* const* d_in, const int* in_sizes, int n_in,
                              void* d_out, int out_size, void* d_ws, size_t ws_size,
                              hipStream_t stream) {
    const float* img   = (const float*)d_in[0];
    const int*   idxp  = (const int*)d_in[1];
    const float* wts   = (const float*)d_in[2];
    const float* alpha = (const float*)d_in[3];
    float* out = (float*)d_out;

    // grid: 3 ch * 128 y-blocks * 16 x-strips
    conv_fused<<<dim3(3 * 128 * 16), dim3(256), 0, stream>>>(
        img, idxp, wts, alpha, out);
}

// Round 2
// 414.078 us; speedup vs baseline: 2.1569x; 2.1569x over previous
//
#include <hip/hip_runtime.h>
#include <stdint.h>

// ---------------------------------------------------------------------------
// ParallaxICBlurModel: depthwise 31x31 conv (3ch x 16 layers) + per-pixel
// alpha-weighted layer sum.  Implicit-GEMM on mfma_f32_16x16x32_bf16.
//   M = 16 pixels (2 rows x 8 cols at x-stride 8), N = 16 layers,
//   K = 31 kernel-rows x 32 (31 taps + 1 zero pad), 8 x-suboffsets d.
// Round 2: coalesced LDS-transpose epilogue (kills 1.2GB alpha over-fetch),
//          single-copy image LDS + alignbit fragment build (4 blocks/CU).
// ---------------------------------------------------------------------------

typedef short short8 __attribute__((ext_vector_type(8)));
typedef float f32x4 __attribute__((ext_vector_type(4)));
typedef uint32_t u32;
typedef u32 u32x4 __attribute__((ext_vector_type(4)));

#define W_IMG    1054         // padded input width/height (H + KS - 1)
#define NKY      31
#define IMG_ROWS 38           // 8 output rows + 30 halo
#define IMG_ROWB 192          // 96 bf16 (one copy), 16B-aligned rows
#define BOFF     (IMG_ROWS * IMG_ROWB)      // 7296
#define B_BYTES  (NKY * 64 * 16)            // 31744
#define LDS_BYTES (BOFF + B_BYTES)          // 39040  (>= 34816 epilogue buf)

__device__ __forceinline__ uint16_t f2bf(float f) {
    uint32_t u = __float_as_uint(f);
    uint32_t r = (u + 0x7fffu + ((u >> 16) & 1u)) >> 16;
    return (uint16_t)r;
}

__global__ __launch_bounds__(256, 4) void conv_fused(
    const float* __restrict__ img, const int* __restrict__ idxp,
    const float* __restrict__ wts, const float* __restrict__ alpha,
    float* __restrict__ out)
{
    __shared__ __align__(16) unsigned char sm[LDS_BYTES];

    const int tid = threadIdx.x;
    const int bid = blockIdx.x;
    const int bx = bid & 15;            // 16 x-strips of 64
    const int by = (bid >> 4) & 127;    // 128 y-blocks of 8
    const int ch = bid >> 11;           // 3 channels
    const int x0 = bx << 6;
    const int y0 = by << 3;

    const float* __restrict__ imgc = img + (size_t)ch * (W_IMG * W_IMG);
    const int idx = *idxp;

    // ---- stage image tile: 38 rows x 96 bf16 (single copy) ----
    for (int it = tid; it < IMG_ROWS * 24; it += 256) {
        int g4 = it % 24;
        int row = it / 24;
        int colbase = x0 + (g4 << 2);
        const float* gp = imgc + (size_t)(y0 + row) * W_IMG + colbase;
        uint64_t pack = 0;
        #pragma unroll
        for (int e = 0; e < 4; ++e) {
            int col = colbase + e;
            float f = (col < W_IMG) ? gp[e] : 0.0f;
            pack |= (uint64_t)f2bf(f) << (16 * e);
        }
        *(uint64_t*)(sm + row * IMG_ROWB + (g4 << 3)) = pack;
    }

    // ---- stage B-fragment table: chunk ky, lane l -> 8 bf16 (16 B) ----
    // B[k][layer]: lane = 16*(k/8) + layer, elem j = k%8, tap kx = 8*(l>>4)+j
    const float* __restrict__ wch = wts + (size_t)ch * 16 * 961;
    for (int it = tid; it < NKY * 64; it += 256) {
        int l = it & 63;
        int ky = it >> 6;
        int layer = l & 15;
        int h = l >> 4;
        union { uint16_t u[8]; short8 s; } pk;
        #pragma unroll
        for (int j = 0; j < 8; ++j) {
            int kx = (h << 3) + j;
            float f = (kx < 31) ? wch[layer * 961 + ky * 31 + kx] : 0.0f;
            pk.u[j] = f2bf(f);
        }
        *(short8*)(sm + BOFF + (it << 4)) = pk.s;
    }

    __syncthreads();

    // ---- main loop ----
    const int lane = tid & 63;
    const int wv = tid >> 6;            // wave -> 2 output rows
    const int lj = lane & 15;           // layer (N / D-col) index
    const int hi = lane >> 4;           // k-group
    const int ix = lane & 7;            // A-row: pixel x sub-index (stride 8)
    const int yp = (lane >> 3) & 1;     // A-row bit3: second output row
    const u32 abase = (u32)(2 * wv + yp) * IMG_ROWB + ((u32)(ix + hi) << 4);

    f32x4 acc[8];
    #pragma unroll
    for (int d = 0; d < 8; ++d) { f32x4 z = {0.f, 0.f, 0.f, 0.f}; acc[d] = z; }

    for (int ky = 0; ky < NKY; ++ky) {
        short8 bfrag = *(const short8*)(sm + BOFF + (((ky << 6) + lane) << 4));
        const unsigned char* ap0 = sm + abase + (u32)ky * IMG_ROWB;
        u32x4 lo = *(const u32x4*)(ap0);        // elems 8s .. 8s+7
        u32x4 hh = *(const u32x4*)(ap0 + 16);   // elems 8s+8 .. 8s+15
        u32 l[8];
        #pragma unroll
        for (int i = 0; i < 4; ++i) { l[i] = lo[i]; l[i + 4] = hh[i]; }
        u32 a[7];
        #pragma unroll
        for (int i = 0; i < 7; ++i)
            a[i] = __builtin_amdgcn_alignbit(l[i + 1], l[i], 16);
        #pragma unroll
        for (int h = 0; h < 4; ++h) {
            union { u32 d[4]; short8 s; } fe, fo;
            #pragma unroll
            for (int i = 0; i < 4; ++i) { fe.d[i] = l[h + i]; fo.d[i] = a[h + i]; }
            acc[2 * h]     = __builtin_amdgcn_mfma_f32_16x16x32_bf16(fe.s, bfrag, acc[2 * h],     0, 0, 0);
            acc[2 * h + 1] = __builtin_amdgcn_mfma_f32_16x16x32_bf16(fo.s, bfrag, acc[2 * h + 1], 0, 0, 0);
        }
    }

    // ---- epilogue: LDS transpose -> coalesced alpha dot + store ----
    __syncthreads();            // all waves done reading img/B areas
    float* bl = (float*)sm;     // blur[512 px][17] = 34816 B (stride-17 pad)

    #pragma unroll
    for (int d = 0; d < 8; ++d) {
        #pragma unroll
        for (int r = 0; r < 4; ++r) {
            int i = 4 * hi + r;                 // D row -> pixel index
            int y = 2 * wv + (i >> 3);
            int x = d + ((i & 7) << 3);
            bl[(y * 64 + x) * 17 + lj] = acc[d][r];
        }
    }
    __syncthreads();

    // thread t -> local pixels t and t+256 (same col, rows r0 and r0+4)
    const int r0 = tid >> 6;
    const int c0 = tid & 63;
    const float* __restrict__ al =
        alpha + (((size_t)idx * 16) << 20) + (size_t)y0 * 1024 + x0;
    float s0 = 0.f, s1 = 0.f;
    #pragma unroll
    for (int l = 0; l < 16; ++l) {
        const float* ap = al + ((size_t)l << 20);
        s0 += bl[tid * 17 + l]         * ap[r0 * 1024 + c0];
        s1 += bl[(tid + 256) * 17 + l] * ap[(r0 + 4) * 1024 + c0];
    }
    float* __restrict__ outc =
        out + ((size_t)ch << 20) + (size_t)y0 * 1024 + x0;
    outc[r0 * 1024 + c0] = s0;
    outc[(r0 + 4) * 1024 + c0] = s1;
}

extern "C" void kernel_launch(void* const* d_in, const int* in_sizes, int n_in,
                              void* d_out, int out_size, void* d_ws, size_t ws_size,
                              hipStream_t stream) {
    const float* img   = (const float*)d_in[0];
    const int*   idxp  = (const int*)d_in[1];
    const float* wts   = (const float*)d_in[2];
    const float* alpha = (const float*)d_in[3];
    float* out = (float*)d_out;

    // grid: 3 ch * 128 y-blocks * 16 x-strips
    conv_fused<<<dim3(3 * 128 * 16), dim3(256), 0, stream>>>(
        img, idxp, wts, alpha, out);
}

// Round 3
// 398.503 us; speedup vs baseline: 2.2412x; 1.0391x over previous
//
#include <hip/hip_runtime.h>
#include <stdint.h>

// ---------------------------------------------------------------------------
// ParallaxICBlurModel: depthwise 31x31 conv (3ch x 16 layers) + per-pixel
// alpha-weighted layer sum.  Implicit-GEMM on mfma_f32_16x16x32_bf16.
//   M = 16 pixels (2 rows x 8 cols at x-stride 8), N = 16 layers,
//   K = 31 kernel-rows x 32 (31 taps + 1 zero pad), 8 x-suboffsets d.
// Round 3: 16-row tiles (4 rows/wave -> B-frag amortized over 16 MFMAs),
//          B prefetch, two-phase coalesced epilogue. 4 blocks/CU.
// ---------------------------------------------------------------------------

typedef short short8 __attribute__((ext_vector_type(8)));
typedef float f32x4 __attribute__((ext_vector_type(4)));
typedef uint32_t u32;
typedef u32 u32x4 __attribute__((ext_vector_type(4)));

#define W_IMG    1054         // padded input width/height (H + KS - 1)
#define NKY      31
#define TILE_Y   16
#define IMG_ROWS 46           // 16 output rows + 30 halo
#define IMG_ROWB 192          // 96 bf16 (one copy), 16B-aligned rows
#define BOFF     (IMG_ROWS * IMG_ROWB)      // 8832
#define B_BYTES  (NKY * 64 * 16)            // 31744
#define LDS_BYTES (BOFF + B_BYTES)          // 40576 (4 blocks/CU; >= 34816 epi)

__device__ __forceinline__ uint16_t f2bf(float f) {
    uint32_t u = __float_as_uint(f);
    uint32_t r = (u + 0x7fffu + ((u >> 16) & 1u)) >> 16;
    return (uint16_t)r;
}

__global__ __launch_bounds__(256, 4) void conv_fused(
    const float* __restrict__ img, const int* __restrict__ idxp,
    const float* __restrict__ wts, const float* __restrict__ alpha,
    float* __restrict__ out)
{
    __shared__ __align__(16) unsigned char sm[LDS_BYTES];

    const int tid = threadIdx.x;
    const int bid = blockIdx.x;
    const int bx = bid & 15;            // 16 x-strips of 64
    const int by = (bid >> 4) & 63;     // 64 y-blocks of 16
    const int ch = bid >> 10;           // 3 channels
    const int x0 = bx << 6;
    const int y0 = by << 4;

    const float* __restrict__ imgc = img + (size_t)ch * (W_IMG * W_IMG);
    const int idx = *idxp;

    // ---- stage image tile: 46 rows x 96 bf16 (single copy) ----
    for (int it = tid; it < IMG_ROWS * 24; it += 256) {
        int g4 = it % 24;
        int row = it / 24;
        int colbase = x0 + (g4 << 2);
        const float* gp = imgc + (size_t)(y0 + row) * W_IMG + colbase;
        uint64_t pack = 0;
        #pragma unroll
        for (int e = 0; e < 4; ++e) {
            int col = colbase + e;
            float f = (col < W_IMG) ? gp[e] : 0.0f;
            pack |= (uint64_t)f2bf(f) << (16 * e);
        }
        *(uint64_t*)(sm + row * IMG_ROWB + (g4 << 3)) = pack;
    }

    // ---- stage B-fragment table: chunk ky, lane l -> 8 bf16 (16 B) ----
    // B[k][layer]: lane = 16*(k/8) + layer, elem j = k%8, tap kx = 8*(l>>4)+j
    const float* __restrict__ wch = wts + (size_t)ch * 16 * 961;
    for (int it = tid; it < NKY * 64; it += 256) {
        int l = it & 63;
        int ky = it >> 6;
        int layer = l & 15;
        int h = l >> 4;
        union { uint16_t u[8]; short8 s; } pk;
        #pragma unroll
        for (int j = 0; j < 8; ++j) {
            int kx = (h << 3) + j;
            float f = (kx < 31) ? wch[layer * 961 + ky * 31 + kx] : 0.0f;
            pk.u[j] = f2bf(f);
        }
        *(short8*)(sm + BOFF + (it << 4)) = pk.s;
    }

    __syncthreads();

    // ---- main loop: wave wv owns output rows y0 + 4*wv + {0,1,2,3} ----
    const int lane = tid & 63;
    const int wv = tid >> 6;
    const int lj = lane & 15;           // layer (N / D-col) index
    const int hi = lane >> 4;           // k-group
    const int ix = lane & 7;            // A-row: pixel x sub-index (stride 8)
    const int yp = (lane >> 3) & 1;     // A-row bit3: second row of a pair
    const u32 abase0 = (u32)(4 * wv + yp) * IMG_ROWB + ((u32)(ix + hi) << 4);
    const u32 abase1 = abase0 + 2 * IMG_ROWB;
    const u32 bbase = BOFF + ((u32)lane << 4);

    f32x4 acc[16];
    #pragma unroll
    for (int d = 0; d < 16; ++d) { f32x4 z = {0.f, 0.f, 0.f, 0.f}; acc[d] = z; }

    short8 bfrag = *(const short8*)(sm + bbase);
    for (int ky = 0; ky < NKY; ++ky) {
        const unsigned char* base = sm + (u32)ky * IMG_ROWB;
        u32x4 lo0 = *(const u32x4*)(base + abase0);
        u32x4 hh0 = *(const u32x4*)(base + abase0 + 16);
        u32x4 lo1 = *(const u32x4*)(base + abase1);
        u32x4 hh1 = *(const u32x4*)(base + abase1 + 16);
        int kyn = (ky < NKY - 1) ? ky + 1 : ky;
        short8 bnext = *(const short8*)(sm + bbase + ((u32)kyn << 10));

        #pragma unroll
        for (int rp = 0; rp < 2; ++rp) {
            u32 l[8];
            #pragma unroll
            for (int i = 0; i < 4; ++i) {
                l[i]     = rp ? lo1[i] : lo0[i];
                l[i + 4] = rp ? hh1[i] : hh0[i];
            }
            u32 a[7];
            #pragma unroll
            for (int i = 0; i < 7; ++i)
                a[i] = __builtin_amdgcn_alignbit(l[i + 1], l[i], 16);
            #pragma unroll
            for (int h = 0; h < 4; ++h) {
                union { u32 d[4]; short8 s; } fe, fo;
                #pragma unroll
                for (int i = 0; i < 4; ++i) { fe.d[i] = l[h + i]; fo.d[i] = a[h + i]; }
                acc[rp * 8 + 2 * h] =
                    __builtin_amdgcn_mfma_f32_16x16x32_bf16(fe.s, bfrag, acc[rp * 8 + 2 * h], 0, 0, 0);
                acc[rp * 8 + 2 * h + 1] =
                    __builtin_amdgcn_mfma_f32_16x16x32_bf16(fo.s, bfrag, acc[rp * 8 + 2 * h + 1], 0, 0, 0);
            }
        }
        bfrag = bnext;
    }

    // ---- epilogue: two phases of 8 rows; LDS transpose -> coalesced dot ----
    float* bl = (float*)sm;             // blur[512 px][17] = 34816 B
    const float* __restrict__ al =
        alpha + (((size_t)idx * 16) << 20) + (size_t)y0 * 1024 + x0;
    float* __restrict__ outc =
        out + ((size_t)ch << 20) + (size_t)y0 * 1024 + x0;
    const int r0 = tid >> 6;
    const int c0 = tid & 63;

    __syncthreads();                    // all waves done reading img/B areas
    #pragma unroll
    for (int p = 0; p < 2; ++p) {
        if ((wv >> 1) == p) {
            #pragma unroll
            for (int rp = 0; rp < 2; ++rp) {
                #pragma unroll
                for (int d = 0; d < 8; ++d) {
                    #pragma unroll
                    for (int r = 0; r < 4; ++r) {
                        int i = 4 * hi + r;             // D row -> pixel index
                        int yph = 4 * (wv & 1) + 2 * rp + (i >> 3);  // 0..7
                        int x = d + ((i & 7) << 3);
                        bl[(yph * 64 + x) * 17 + lj] = acc[rp * 8 + d][r];
                    }
                }
            }
        }
        __syncthreads();
        float s0 = 0.f, s1 = 0.f;
        #pragma unroll
        for (int l = 0; l < 16; ++l) {
            const float* ap = al + ((size_t)l << 20);
            s0 += bl[tid * 17 + l]         * ap[(size_t)(8 * p + r0) * 1024 + c0];
            s1 += bl[(tid + 256) * 17 + l] * ap[(size_t)(8 * p + r0 + 4) * 1024 + c0];
        }
        outc[(size_t)(8 * p + r0) * 1024 + c0] = s0;
        outc[(size_t)(8 * p + r0 + 4) * 1024 + c0] = s1;
        if (p == 0) __syncthreads();    // phase-1 writers wait for readers
    }
}

extern "C" void kernel_launch(void* const* d_in, const int* in_sizes, int n_in,
                              void* d_out, int out_size, void* d_ws, size_t ws_size,
                              hipStream_t stream) {
    const float* img   = (const float*)d_in[0];
    const int*   idxp  = (const int*)d_in[1];
    const float* wts   = (const float*)d_in[2];
    const float* alpha = (const float*)d_in[3];
    float* out = (float*)d_out;

    // grid: 3 ch * 64 y-blocks * 16 x-strips
    conv_fused<<<dim3(3 * 64 * 16), dim3(256), 0, stream>>>(
        img, idxp, wts, alpha, out);
}